// Round 14
// baseline (284.224 us; speedup 1.0000x reference)
//
#include <hip/hip_runtime.h>
#include <hip/hip_bf16.h>

#define TT 512
#define BPB 2                 // batches per block (wave-pair design)
#define NBLK (2048 / BPB)     // 1024 blocks = 4 per CU
#define OUTD 64

typedef __attribute__((ext_vector_type(8))) short short8;
typedef __attribute__((ext_vector_type(4))) float f32x4;
typedef __attribute__((ext_vector_type(4))) unsigned uint4v;

__device__ __forceinline__ short f2bf(float x) {  // RNE float->bf16 (staging)
    union { float f; unsigned u; } v; v.f = x;
    unsigned r = (v.u + 0x7FFFu + ((v.u >> 16) & 1u)) >> 16;
    return (short)r;
}
__device__ __forceinline__ unsigned cvtpk2(float lo, float hi) {  // pack 2 bf16
    unsigned r;
    asm("v_cvt_pk_bf16_f32 %0, %1, %2" : "=v"(r) : "v"(lo), "v"(hi));
    return r;
}
__device__ __forceinline__ float sigm(float x) {
    return __builtin_amdgcn_rcpf(1.f + __expf(-x));
}
__device__ __forceinline__ float tanh_fast(float x) {
    return 2.f * sigm(2.f * x) - 1.f;
}

#define ACT_UPDATE(acc, c, hval)                                   \
    {                                                              \
        float gi = sigm((acc)[0]);                                 \
        float gf = sigm((acc)[1]);                                 \
        float gg = tanh_fast((acc)[2]);                            \
        float go = sigm((acc)[3]);                                 \
        (c) = gf * (c) + gi * gg;                                  \
        (hval) = go * tanh_fast((c));                              \
    }

#define MFMA __builtin_amdgcn_mfma_f32_16x16x32_bf16

// select acc[tsel] without dynamic indexing: 3-level mux tree (28 cndmask)
#define SELECT(mine, acc)                                          \
    f32x4 mine;                                                    \
    {                                                              \
        f32x4 m01 = (tsel & 1) ? (acc)[1] : (acc)[0];              \
        f32x4 m23 = (tsel & 1) ? (acc)[3] : (acc)[2];              \
        f32x4 m45 = (tsel & 1) ? (acc)[5] : (acc)[4];              \
        f32x4 m67 = (tsel & 1) ? (acc)[7] : (acc)[6];              \
        f32x4 mA  = (tsel & 2) ? m23 : m01;                        \
        f32x4 mB  = (tsel & 2) ? m67 : m45;                        \
        mine = (tsel & 4) ? mB : mA;                               \
    }

// repack spread h (lane owns (u=4*(col>>1)+kg, b=col&1)) into B-frag:
// lane (col,kg) needs h[k=kg*8+j][col&1]; src lane = 16*(j&3)+4*kg+2*(j>>2)+b
#define REPACK(h, d0, d1, d2, d3)                                  \
    {                                                              \
        const int base = 4 * kg + b;                               \
        float s0 = __shfl((h), base);                              \
        float s1 = __shfl((h), base + 16);                         \
        float s2 = __shfl((h), base + 32);                         \
        float s3 = __shfl((h), base + 48);                         \
        float s4 = __shfl((h), base + 2);                          \
        float s5 = __shfl((h), base + 18);                         \
        float s6 = __shfl((h), base + 34);                         \
        float s7 = __shfl((h), base + 50);                         \
        d0 = cvtpk2(s0, s1); d1 = cvtpk2(s2, s3);                  \
        d2 = cvtpk2(s4, s5); d3 = cvtpk2(s6, s7);                  \
    }

__global__ __launch_bounds__(128, 2) void lstm2_pairwave_kernel(
    const float* __restrict__ imu,
    const float* __restrict__ w_ih0, const float* __restrict__ w_hh0,
    const float* __restrict__ b_ih0, const float* __restrict__ b_hh0,
    const float* __restrict__ w_ih1, const float* __restrict__ w_hh1,
    const float* __restrict__ b_ih1, const float* __restrict__ b_hh1,
    const float* __restrict__ wf, const float* __restrict__ bf,
    const float* __restrict__ wn, const float* __restrict__ bn,
    float* __restrict__ out)
{
    const int tid  = threadIdx.x;
    const int l    = tid & 63;
    const int wv   = tid >> 6;        // 0 = layer-1 wave, 1 = layer-2 wave
    const int col  = l & 15;
    const int kg   = l >> 4;
    const int b    = col & 1;         // batch (replicated across col pairs)
    const int tsel = col >> 1;        // owned tile after select
    const int unit = 4 * tsel + kg;   // owned hidden unit

    __shared__ __align__(16) short    xfrag[TT + 2][BPB][8];  // [t][b][k] bf16, k>=6 zero
    __shared__ __align__(16) unsigned h1buf[2][BPB][4][4];    // [parity][b][kg][dword]
    __shared__ __align__(16) float    lasth[BPB][36];

    // ---- stage x (2 batches)
    {
        const int bg0 = blockIdx.x * BPB;
        for (int p = tid; p < BPB * TT; p += 128) {
            const int bb = p >> 9;           // 0..1
            const int t  = p & (TT - 1);
            const float* src = imu + ((size_t)(bg0 + bb) * TT + t) * 6;
            float2 a0 = *(const float2*)(src);
            float2 a1 = *(const float2*)(src + 2);
            float2 a2 = *(const float2*)(src + 4);
            unsigned* dst = (unsigned*)&xfrag[t][bb][0];
            dst[0] = (unsigned short)f2bf(a0.x) | ((unsigned)(unsigned short)f2bf(a0.y) << 16);
            dst[1] = (unsigned short)f2bf(a1.x) | ((unsigned)(unsigned short)f2bf(a1.y) << 16);
            dst[2] = (unsigned short)f2bf(a2.x) | ((unsigned)(unsigned short)f2bf(a2.y) << 16);
            dst[3] = 0u;
        }
        short* px = &xfrag[TT][0][0];
        if (tid < 2 * BPB * 8) px[tid] = 0;
    }

    // ---- A-fragments: 8 tiles per wave (whole layer). Proven mapping (R11):
    // row m=col -> gate G=(m&3)*32+4*tau+(m>>2); D reg r = gate-type r of unit 4tau+kg.
    const int m = col;
    short8 AS[8], AX[8];   // AS: recurrent (Whh); AX: input (Wih0-x / Wih1-h1)
    f32x4 bias[8];
    #pragma unroll
    for (int tp = 0; tp < 8; ++tp) {
        const int G = (m & 3) * 32 + 4 * tp + (m >> 2);
        const int u = 4 * tp + kg;
        if (wv == 0) {
            #pragma unroll
            for (int j = 0; j < 8; ++j) {
                AX[tp][j] = (kg == 0 && j < 6) ? f2bf(w_ih0[G * 6 + j]) : (short)0;
                AS[tp][j] = f2bf(w_hh0[G * 32 + kg * 8 + j]);
            }
            #pragma unroll
            for (int r = 0; r < 4; ++r)
                bias[tp][r] = b_ih0[r * 32 + u] + b_hh0[r * 32 + u];
        } else {
            #pragma unroll
            for (int j = 0; j < 8; ++j) {
                AX[tp][j] = f2bf(w_ih1[G * 32 + kg * 8 + j]);
                AS[tp][j] = f2bf(w_hh1[G * 32 + kg * 8 + j]);
            }
            #pragma unroll
            for (int r = 0; r < 4; ++r)
                bias[tp][r] = b_ih1[r * 32 + u] + b_hh1[r * 32 + u];
        }
    }

    float cst = 0.f;                  // cell state of owned (unit, batch)
    short8 hfrag = (short8)0;         // wv0: h1 B-frag; wv1: h2 B-frag (in regs!)
    f32x4 accx[8];                    // wv0 only: x-partial for current step
    short8 xvE = (short8)0, xvO = (short8)0;

    __syncthreads();

    // ---- prologue: prime accx = Wih0*x(0)+bias; prefetch x(1)
    if (wv == 0) {
        short8 xv0 = *(const short8*)&xfrag[0][b][0];
        #pragma unroll
        for (int tp = 0; tp < 8; ++tp)
            accx[tp] = MFMA(AX[tp], xv0, bias[tp], 0, 0, 0);
        xvE = *(const short8*)&xfrag[1][b][0];
    }

    // ======== STEP(I): L1 computes gates1(I) -> h1(I); L2 computes gates2(I-1).
    // h1(I) written to parity I&1; L2 reads h1(I-1) at parity (I-1)&1. 1 barrier.
#define STEP(I, RP, WP, XVC, XVL, ACT2)                                         \
    {                                                                           \
        if (wv == 0) {                                                          \
            f32x4 acc[8];                                                       \
            _Pragma("unroll")                                                   \
            for (int tp = 0; tp < 8; ++tp)                                      \
                acc[tp] = MFMA(AS[tp], hfrag, accx[tp], 0, 0, 0);               \
            SELECT(mine, acc);                                                  \
            float h;                                                            \
            ACT_UPDATE(mine, cst, h);                                           \
            unsigned d0, d1, d2, d3;                                            \
            REPACK(h, d0, d1, d2, d3);                                          \
            union { unsigned u[4]; short8 s; } hu;                              \
            hu.u[0] = d0; hu.u[1] = d1; hu.u[2] = d2; hu.u[3] = d3;             \
            hfrag = hu.s;                                                       \
            if (col < 2)                                                        \
                *(uint4v*)&h1buf[WP][col][kg][0] = (uint4v){d0, d1, d2, d3};    \
            _Pragma("unroll")                                                   \
            for (int tp = 0; tp < 8; ++tp)                                      \
                accx[tp] = MFMA(AX[tp], XVC, bias[tp], 0, 0, 0);                \
            XVL = *(const short8*)&xfrag[(I) + 2][b][0];                        \
        } else if (ACT2) {                                                      \
            short8 h1v = *(const short8*)&h1buf[RP][b][kg][0];                  \
            f32x4 acc[8];                                                       \
            _Pragma("unroll")                                                   \
            for (int tp = 0; tp < 8; ++tp)                                      \
                acc[tp] = MFMA(AS[tp], hfrag, bias[tp], 0, 0, 0);               \
            _Pragma("unroll")                                                   \
            for (int tp = 0; tp < 8; ++tp)                                      \
                acc[tp] = MFMA(AX[tp], h1v, acc[tp], 0, 0, 0);                  \
            SELECT(mine, acc);                                                  \
            float h;                                                            \
            ACT_UPDATE(mine, cst, h);                                           \
            unsigned d0, d1, d2, d3;                                            \
            REPACK(h, d0, d1, d2, d3);                                          \
            union { unsigned u[4]; short8 s; } hu;                              \
            hu.u[0] = d0; hu.u[1] = d1; hu.u[2] = d2; hu.u[3] = d3;             \
            hfrag = hu.s;                                                       \
        }                                                                       \
        __syncthreads();                                                        \
    }

    STEP(0, 0, 0, xvE, xvO, 0)           // L1 only (h1(-1)=0 in hfrag)
    #pragma unroll 1
    for (int t = 1; t < TT - 1; t += 2) {
        STEP(t,     0, 1, xvO, xvE, 1)   // odd I: read parity 0, write 1
        STEP(t + 1, 1, 0, xvE, xvO, 1)   // even I: read parity 1, write 0
    }
    STEP(TT - 1, 0, 1, xvO, xvE, 1)      // I=511 (x-prefetch hits pad rows)

    // ======== epilogue: L2 gates2(511) -> lasth (fp32) ========
    if (wv == 1) {
        short8 h1v = *(const short8*)&h1buf[1][b][kg][0];   // h1(511), parity 1
        f32x4 acc[8];
        #pragma unroll
        for (int tp = 0; tp < 8; ++tp)
            acc[tp] = MFMA(AS[tp], hfrag, bias[tp], 0, 0, 0);
        #pragma unroll
        for (int tp = 0; tp < 8; ++tp)
            acc[tp] = MFMA(AX[tp], h1v, acc[tp], 0, 0, 0);
        SELECT(mine, acc);
        float h;
        ACT_UPDATE(mine, cst, h);
        lasth[b][unit] = h;
    }
    __syncthreads();

    // ======== heads: 128 threads = 2 batches x 64 outputs ========
    {
        const int bb = tid >> 6;           // 0..1 (wave-uniform)
        const int o  = tid & 63;
        float accF = bf[o], accN = bn[o];
        const float4* wf4 = (const float4*)(wf + o * 32);
        const float4* wn4 = (const float4*)(wn + o * 32);
        const float4* hv4 = (const float4*)&lasth[bb][0];
        #pragma unroll
        for (int k = 0; k < 8; ++k) {
            float4 h4 = hv4[k];
            float4 f4 = wf4[k];
            float4 n4 = wn4[k];
            accF += f4.x * h4.x + f4.y * h4.y + f4.z * h4.z + f4.w * h4.w;
            accN += n4.x * h4.x + n4.y * h4.y + n4.z * h4.z + n4.w * h4.w;
        }
        const size_t bg = (size_t)blockIdx.x * BPB + bb;
        out[bg * OUTD + o] = accF;
        out[(size_t)2048 * OUTD + bg * OUTD + o] = __expf(accN);
    }
}

extern "C" void kernel_launch(void* const* d_in, const int* in_sizes, int n_in,
                              void* d_out, int out_size, void* d_ws, size_t ws_size,
                              hipStream_t stream) {
    const float* imu   = (const float*)d_in[0];
    const float* w_ih0 = (const float*)d_in[1];
    const float* w_hh0 = (const float*)d_in[2];
    const float* b_ih0 = (const float*)d_in[3];
    const float* b_hh0 = (const float*)d_in[4];
    const float* w_ih1 = (const float*)d_in[5];
    const float* w_hh1 = (const float*)d_in[6];
    const float* b_ih1 = (const float*)d_in[7];
    const float* b_hh1 = (const float*)d_in[8];
    const float* wf    = (const float*)d_in[9];
    const float* bf    = (const float*)d_in[10];
    const float* wn    = (const float*)d_in[11];
    const float* bn    = (const float*)d_in[12];
    float* out = (float*)d_out;

    lstm2_pairwave_kernel<<<dim3(NBLK), dim3(128), 0, stream>>>(
        imu, w_ih0, w_hh0, b_ih0, b_hh0,
        w_ih1, w_hh1, b_ih1, b_hh1,
        wf, bf, wn, bn, out);
}